// Round 2
// baseline (250.758 us; speedup 1.0000x reference)
//
#include <hip/hip_runtime.h>
#include <math.h>

// Problem constants
static constexpr int NN   = 8192;     // nodes
static constexpr int EE   = 262144;   // edges
static constexpr int KIN  = 1024;     // in features
static constexpr int HID  = 256;      // hidden
static constexpr int NOUT = 40;       // out classes

typedef float  f32x4  __attribute__((ext_vector_type(4)));
typedef short  short8 __attribute__((ext_vector_type(8)));

// ---------------- workspace layout (bytes) ----------------
static constexpr size_t SZ_BITMAP = (size_t)NN * NN / 8;       // 8 MB dedupe bitmap
static constexpr size_t SZ_RC     = (size_t)NN * 4;            // row counts
static constexpr size_t SZ_RF     = (size_t)NN * 4;            // row fill cursors
static constexpr size_t SZ_UC     = 256;                       // unique counter
static constexpr size_t SZ_ROFF   = (((size_t)(NN + 1) * 4 + 255) / 256) * 256;
static constexpr size_t SZ_DIS    = (size_t)NN * 4;            // deg^-1/2
static constexpr size_t SZ_UK     = (size_t)EE * 4;            // unique packed keys
static constexpr size_t SZ_CSR    = (size_t)EE * 4;            // csr dst lists
static constexpr size_t SZ_H1     = (size_t)NN * HID * 4;      // X@W1
static constexpr size_t SZ_G2     = (size_t)NN * NOUT * 4;     // H1agg@W2
static constexpr size_t SZ_WP     = (size_t)KIN * HID * 2;     // one bf16 half of W1 pack

static constexpr size_t O_BITMAP = 0;
static constexpr size_t O_RC     = O_BITMAP + SZ_BITMAP;
static constexpr size_t O_RF     = O_RC + SZ_RC;
static constexpr size_t O_UC     = O_RF + SZ_RF;
static constexpr size_t MEMSET_BYTES = O_UC + SZ_UC;           // one memset covers all of the above
static constexpr size_t O_ROFF   = MEMSET_BYTES;
static constexpr size_t O_DIS    = O_ROFF + SZ_ROFF;
static constexpr size_t O_UK     = O_DIS + SZ_DIS;
static constexpr size_t O_CSR    = O_UK + SZ_UK;
static constexpr size_t O_H1     = O_CSR + SZ_CSR;
static constexpr size_t O_H1A    = O_H1 + SZ_H1;
static constexpr size_t O_G2     = O_H1A + SZ_H1;
static constexpr size_t O_WH     = O_G2 + SZ_G2;
static constexpr size_t O_WL     = O_WH + SZ_WP;
// total ~28.4 MB

// ---------------- helpers ----------------
__device__ inline unsigned short f2bf(float f) {        // f32 -> bf16 bits, RNE
    unsigned u = __float_as_uint(f);
    return (unsigned short)((u + 0x7fffu + ((u >> 16) & 1u)) >> 16);
}
__device__ inline float bf2f(unsigned short h) {
    return __uint_as_float((unsigned)h << 16);
}

// ---------------- graph construction ----------------

// Dedupe edges via bitmap; count distinct out-degree per src; emit unique packed keys.
// int64-vs-int32 layout detect folded in (odd 32-bit words all zero over first 32 values => int64).
__global__ __launch_bounds__(256) void ingest_kernel(const int* __restrict__ e,
        unsigned* __restrict__ bitmap, int* __restrict__ rowc,
        unsigned* __restrict__ ukeys, int* __restrict__ ucount) {
    __shared__ int sflag;
    if (threadIdx.x == 0) {
        int orv = 0;
        #pragma unroll
        for (int j = 1; j < 64; j += 2) orv |= e[j];
        sflag = (orv == 0) ? 1 : 0;
    }
    __syncthreads();
    const int i = blockIdx.x * 256 + threadIdx.x;   // grid exactly covers EE
    int s, d;
    if (sflag) { s = e[2 * i]; d = e[2 * EE + 2 * i]; }   // int64: low words
    else       { s = e[i];     d = e[EE + i]; }            // int32
    const unsigned key = ((unsigned)s << 13) | (unsigned)d;
    const unsigned w = key >> 5, b = 1u << (key & 31u);
    const unsigned old = atomicOr(&bitmap[w], b);
    if (!(old & b)) {                    // first toucher of this (s,d): it's unique
        atomicAdd(&rowc[s], 1);
        const int idx = atomicAdd(ucount, 1);
        ukeys[idx] = key;
    }
}

// Exclusive prefix sum of row counts (8192) + d_is = rsqrt(deg), deg = count+1 (identity).
__global__ __launch_bounds__(1024) void scan_kernel(const int* __restrict__ rowc,
        int* __restrict__ roff, float* __restrict__ dis) {
    __shared__ int ps[1024];
    const int t = threadIdx.x;
    const int base = t * 8;
    int v[8];
    int s = 0;
    #pragma unroll
    for (int j = 0; j < 8; ++j) { v[j] = rowc[base + j]; s += v[j]; }
    ps[t] = s;
    __syncthreads();
    for (int o = 1; o < 1024; o <<= 1) {
        int add = (t >= o) ? ps[t - o] : 0;
        __syncthreads();
        ps[t] += add;
        __syncthreads();
    }
    int run = ps[t] - s;   // exclusive prefix of this thread's chunk
    #pragma unroll
    for (int j = 0; j < 8; ++j) {
        roff[base + j] = run;
        run += v[j];
        dis[base + j] = rsqrtf((float)(v[j] + 1));
    }
    if (t == 1023) roff[NN] = run;
}

// Scatter unique keys into CSR slots.
__global__ __launch_bounds__(256) void place_kernel(const unsigned* __restrict__ ukeys,
        const int* __restrict__ ucount, const int* __restrict__ roff,
        int* __restrict__ rfill, unsigned* __restrict__ csr) {
    const int i = blockIdx.x * 256 + threadIdx.x;
    if (i >= *ucount) return;
    const unsigned key = ukeys[i];
    const int s = (int)(key >> 13);
    const unsigned d = key & 8191u;
    const int slot = atomicAdd(&rfill[s], 1);
    csr[roff[s] + slot] = d;
}

// ---------------- W1 split+pack into MFMA B-fragment layout ----------------
// Frag (nfg 0..15, kt 0..31): lane l holds B[k = kt*32 + (l>>4)*8 + j][n = nfg*16 + (l&15)], j=0..7.
// Stored contiguously: 16B per (nfg,kt,lane).
__global__ __launch_bounds__(256) void wsplit_kernel(const float* __restrict__ W1,
        unsigned short* __restrict__ Wh, unsigned short* __restrict__ Wl) {
    const int id  = blockIdx.x * 256 + threadIdx.x;   // 0..32767
    const int l   = id & 63;
    const int kt  = (id >> 6) & 31;
    const int nfg = id >> 11;
    const int k0  = kt * 32 + ((l >> 4) << 3);
    const int n   = (nfg << 4) + (l & 15);
    unsigned hh[8], ll[8];
    #pragma unroll
    for (int j = 0; j < 8; ++j) {
        const float f = W1[(size_t)(k0 + j) * HID + n];
        const unsigned short h = f2bf(f);
        hh[j] = h;
        ll[j] = f2bf(f - bf2f(h));
    }
    uint4 vh, vl;
    vh.x = hh[0] | (hh[1] << 16); vh.y = hh[2] | (hh[3] << 16);
    vh.z = hh[4] | (hh[5] << 16); vh.w = hh[6] | (hh[7] << 16);
    vl.x = ll[0] | (ll[1] << 16); vl.y = ll[2] | (ll[3] << 16);
    vl.z = ll[4] | (ll[5] << 16); vl.w = ll[6] | (ll[7] << 16);
    ((uint4*)Wh)[id] = vh;
    ((uint4*)Wl)[id] = vl;
}

// ---------------- GEMM 1: H1 = X @ W1 via split-bf16 MFMA ----------------
// C = Xh*Wh + Xh*Wl + Xl*Wh (f32 accumulate); dropped Xl*Wl term ~2^-18 relative.
// BM=32, BN=256 (full width -> X read exactly once). 256 threads = 4 waves, wave w owns cols w*64..+63.
// K staged to LDS in 4 chunks of 256 as bf16 hi/lo, row stride 272 (even bank spread for b128 reads).
static constexpr int RS = 272;   // LDS row stride in bf16 elements

__global__ __launch_bounds__(256) void gemm1_kernel(const float* __restrict__ X,
        const unsigned short* __restrict__ Wh, const unsigned short* __restrict__ Wl,
        float* __restrict__ H) {
    __shared__ unsigned short Ah[32 * RS];
    __shared__ unsigned short Al[32 * RS];
    const int t    = threadIdx.x;
    const int bm   = blockIdx.x;          // 0..255
    const int lane = t & 63;
    const int w    = t >> 6;              // wave id 0..3
    // staging mapping: thread loads float4s of row sr at k = sc + i*32
    const int sr = t >> 3;                // 0..31
    const int sc = (t & 7) << 2;          // 0..28
    const float* Xp = X + (size_t)(bm * 32 + sr) * KIN + sc;
    const short8* Bhp = (const short8*)Wh;
    const short8* Blp = (const short8*)Wl;

    f32x4 acc[2][4];
    #pragma unroll
    for (int mf = 0; mf < 2; ++mf)
        #pragma unroll
        for (int nf = 0; nf < 4; ++nf) acc[mf][nf] = (f32x4)0.f;

    // chunk-0 X prefetch
    float4 px[8];
    #pragma unroll
    for (int i = 0; i < 8; ++i) px[i] = *(const float4*)(Xp + i * 32);

    // B frags for kt=0
    short8 bch[4], bcl[4], bnh[4], bnl[4];
    #pragma unroll
    for (int nf = 0; nf < 4; ++nf) {
        const int fi = ((w * 4 + nf) * 32 + 0) * 64 + lane;
        bch[nf] = Bhp[fi];
        bcl[nf] = Blp[fi];
    }

    for (int ch = 0; ch < 4; ++ch) {
        __syncthreads();                       // previous chunk's LDS reads done
        #pragma unroll
        for (int i = 0; i < 8; ++i) {
            const int k0 = sc + i * 32;
            const float4 v = px[i];
            const float fv[4] = {v.x, v.y, v.z, v.w};
            ushort4 h4, l4;
            unsigned short hs[4], ls[4];
            #pragma unroll
            for (int j = 0; j < 4; ++j) {
                hs[j] = f2bf(fv[j]);
                ls[j] = f2bf(fv[j] - bf2f(hs[j]));
            }
            h4.x = hs[0]; h4.y = hs[1]; h4.z = hs[2]; h4.w = hs[3];
            l4.x = ls[0]; l4.y = ls[1]; l4.z = ls[2]; l4.w = ls[3];
            *(ushort4*)&Ah[sr * RS + k0] = h4;
            *(ushort4*)&Al[sr * RS + k0] = l4;
        }
        __syncthreads();                       // LDS tile ready
        if (ch < 3) {                          // prefetch next X chunk (hidden under MFMAs)
            Xp += 256;
            #pragma unroll
            for (int i = 0; i < 8; ++i) px[i] = *(const float4*)(Xp + i * 32);
        }
        #pragma unroll
        for (int kk = 0; kk < 8; ++kk) {
            const int kt = ch * 8 + kk;
            // A frags from LDS
            short8 ah[2], al[2];
            #pragma unroll
            for (int mf = 0; mf < 2; ++mf) {
                const int off = (mf * 16 + (lane & 15)) * RS + kk * 32 + ((lane >> 4) << 3);
                ah[mf] = *(const short8*)&Ah[off];
                al[mf] = *(const short8*)&Al[off];
            }
            // prefetch B frags for kt+1
            if (kt < 31) {
                #pragma unroll
                for (int nf = 0; nf < 4; ++nf) {
                    const int fi = ((w * 4 + nf) * 32 + kt + 1) * 64 + lane;
                    bnh[nf] = Bhp[fi];
                    bnl[nf] = Blp[fi];
                }
            }
            // 3-term split MFMAs
            #pragma unroll
            for (int mf = 0; mf < 2; ++mf)
                #pragma unroll
                for (int nf = 0; nf < 4; ++nf) {
                    f32x4 c = acc[mf][nf];
                    c = __builtin_amdgcn_mfma_f32_16x16x32_bf16(ah[mf], bch[nf], c, 0, 0, 0);
                    c = __builtin_amdgcn_mfma_f32_16x16x32_bf16(ah[mf], bcl[nf], c, 0, 0, 0);
                    c = __builtin_amdgcn_mfma_f32_16x16x32_bf16(al[mf], bch[nf], c, 0, 0, 0);
                    acc[mf][nf] = c;
                }
            #pragma unroll
            for (int nf = 0; nf < 4; ++nf) { bch[nf] = bnh[nf]; bcl[nf] = bnl[nf]; }
        }
    }
    // epilogue: C/D layout col=lane&15, row=(lane>>4)*4+r (m89-verified)
    #pragma unroll
    for (int mf = 0; mf < 2; ++mf)
        #pragma unroll
        for (int nf = 0; nf < 4; ++nf)
            #pragma unroll
            for (int r = 0; r < 4; ++r) {
                const int row = bm * 32 + mf * 16 + ((lane >> 4) << 2) + r;
                const int col = w * 64 + nf * 16 + (lane & 15);
                H[(size_t)row * HID + col] = acc[mf][nf][r];
            }
}

// ---------------- SpMM agg 1 + bias + ReLU ----------------
__global__ __launch_bounds__(256) void agg1_kernel(const float* __restrict__ H1,
        const int* __restrict__ roff, const unsigned* __restrict__ csr,
        const float* __restrict__ dis, const float* __restrict__ b1,
        float* __restrict__ out) {
    __shared__ unsigned dl[256];
    __shared__ float    wl[256];
    const int s = blockIdx.x;
    const int c = threadIdx.x;
    const float ds = dis[s];
    float acc = ds * ds * H1[(size_t)s * HID + c];      // identity term
    const int beg = roff[s], end = roff[s + 1];
    for (int chk = beg; chk < end; chk += 256) {
        const int n = min(256, end - chk);
        __syncthreads();
        if (c < n) {
            const unsigned d = csr[chk + c];
            dl[c] = d;
            wl[c] = ds * dis[d];
        }
        __syncthreads();
        #pragma unroll 4
        for (int i = 0; i < n; ++i)
            acc = fmaf(wl[i], H1[(size_t)dl[i] * HID + c], acc);
    }
    out[(size_t)s * HID + c] = fmaxf(acc + b1[c], 0.f);
}

// ---------------- GEMM 2: G2 = H1A @ W2 (b2 added after agg) ----------------
__global__ __launch_bounds__(256) void gemm2_kernel(const float* __restrict__ H,
        const float* __restrict__ W2, float* __restrict__ G) {
    __shared__ float w2s[HID * NOUT];   // 40 KB
    const int t = threadIdx.x;
    for (int i = t; i < HID * NOUT; i += 256) w2s[i] = W2[i];
    __syncthreads();
    const int row = blockIdx.x * 64 + (t >> 2);
    const int cg  = (t & 3) * 10;
    float acc[10];
    #pragma unroll
    for (int j = 0; j < 10; ++j) acc[j] = 0.f;
    const float* hp = H + (size_t)row * HID;
    for (int k = 0; k < HID; k += 4) {
        const float4 h4 = *(const float4*)(hp + k);
        #pragma unroll
        for (int j = 0; j < 10; ++j) {
            acc[j] = fmaf(h4.x, w2s[(k + 0) * NOUT + cg + j],
                     fmaf(h4.y, w2s[(k + 1) * NOUT + cg + j],
                     fmaf(h4.z, w2s[(k + 2) * NOUT + cg + j],
                     fmaf(h4.w, w2s[(k + 3) * NOUT + cg + j], acc[j]))));
        }
    }
    #pragma unroll
    for (int j = 0; j < 10; ++j) G[(size_t)row * NOUT + cg + j] = acc[j];
}

// ---------------- SpMM agg 2 + b2 + log_softmax, writes d_out ----------------
__global__ __launch_bounds__(256) void agg2_kernel(const float* __restrict__ G,
        const int* __restrict__ roff, const unsigned* __restrict__ csr,
        const float* __restrict__ dis, const float* __restrict__ b2,
        float* __restrict__ out) {
    const int wv   = threadIdx.x >> 6;
    const int lane = threadIdx.x & 63;
    const int s = blockIdx.x * 4 + wv;       // one wave per row
    const bool act = lane < NOUT;
    const float ds = dis[s];
    float acc = act ? ds * ds * G[(size_t)s * NOUT + lane] : 0.f;
    const int beg = roff[s], end = roff[s + 1];
    for (int e = beg; e < end; ++e) {
        const unsigned d = csr[e];
        const float wt = ds * dis[d];
        if (act) acc = fmaf(wt, G[(size_t)d * NOUT + lane], acc);
    }
    if (act) acc += b2[lane];
    float v = act ? acc : -INFINITY;
    #pragma unroll
    for (int o = 32; o > 0; o >>= 1) v = fmaxf(v, __shfl_xor(v, o));
    float ex = act ? expf(acc - v) : 0.f;
    #pragma unroll
    for (int o = 32; o > 0; o >>= 1) ex += __shfl_xor(ex, o);
    const float lz = v + logf(ex);
    if (act) out[(size_t)s * NOUT + lane] = acc - lz;
}

// ---------------- launch ----------------
extern "C" void kernel_launch(void* const* d_in, const int* in_sizes, int n_in,
                              void* d_out, int out_size, void* d_ws, size_t ws_size,
                              hipStream_t stream) {
    (void)in_sizes; (void)n_in; (void)out_size; (void)ws_size;
    const float* x  = (const float*)d_in[0];
    const int*   ei = (const int*)d_in[1];
    const float* W1 = (const float*)d_in[2];
    const float* b1 = (const float*)d_in[3];
    const float* W2 = (const float*)d_in[4];
    const float* b2 = (const float*)d_in[5];
    float* out = (float*)d_out;
    char* ws = (char*)d_ws;

    unsigned*       bitmap = (unsigned*)(ws + O_BITMAP);
    int*            rowc   = (int*)(ws + O_RC);
    int*            rfill  = (int*)(ws + O_RF);
    int*            ucnt   = (int*)(ws + O_UC);
    int*            roff   = (int*)(ws + O_ROFF);
    float*          dis    = (float*)(ws + O_DIS);
    unsigned*       ukeys  = (unsigned*)(ws + O_UK);
    unsigned*       csr    = (unsigned*)(ws + O_CSR);
    float*          H1     = (float*)(ws + O_H1);
    float*          H1A    = (float*)(ws + O_H1A);
    float*          G2     = (float*)(ws + O_G2);
    unsigned short* Wh     = (unsigned short*)(ws + O_WH);
    unsigned short* Wl     = (unsigned short*)(ws + O_WL);

    // zero bitmap + counters (ws is re-poisoned to 0xAA before every timed call)
    hipMemsetAsync(ws, 0, MEMSET_BYTES, stream);

    ingest_kernel<<<EE / 256, 256, 0, stream>>>(ei, bitmap, rowc, ukeys, ucnt);
    scan_kernel<<<1, 1024, 0, stream>>>(rowc, roff, dis);
    place_kernel<<<EE / 256, 256, 0, stream>>>(ukeys, ucnt, roff, rfill, csr);

    wsplit_kernel<<<(KIN * HID / 8) / 256, 256, 0, stream>>>(W1, Wh, Wl);
    gemm1_kernel<<<NN / 32, 256, 0, stream>>>(x, Wh, Wl, H1);
    agg1_kernel<<<NN, 256, 0, stream>>>(H1, roff, csr, dis, b1, H1A);
    gemm2_kernel<<<NN / 64, 256, 0, stream>>>(H1A, W2, G2);
    agg2_kernel<<<NN / 4, 256, 0, stream>>>(G2, roff, csr, dis, b2, out);
}

// Round 5
// 191.257 us; speedup vs baseline: 1.3111x; 1.3111x over previous
//
#include <hip/hip_runtime.h>
#include <math.h>

// Problem constants
static constexpr int NN   = 8192;     // nodes
static constexpr int EE   = 262144;   // edges
static constexpr int KIN  = 1024;     // in features
static constexpr int HID  = 256;      // hidden
static constexpr int NOUT = 40;       // out classes

typedef float  f32x4  __attribute__((ext_vector_type(4)));
typedef short  short8 __attribute__((ext_vector_type(8)));

// ---------------- workspace layout (bytes) ----------------
static constexpr size_t SZ_BITMAP = (size_t)NN * NN / 8;       // 8 MB dedupe bitmap
static constexpr size_t SZ_RC     = (size_t)NN * 4;            // row counts
static constexpr size_t SZ_ROFF   = (((size_t)(NN + 1) * 4 + 255) / 256) * 256;
static constexpr size_t SZ_DIS    = (size_t)NN * 4;            // deg^-1/2
static constexpr size_t SZ_CSR    = (size_t)EE * 4;            // csr dst lists
static constexpr size_t SZ_H1     = (size_t)NN * HID * 4;      // X@W1
static constexpr size_t SZ_G2     = (size_t)NN * NOUT * 4;     // H1agg@W2
static constexpr size_t SZ_WP     = (size_t)KIN * HID * 2;     // one bf16 half of W1 pack

static constexpr size_t O_BITMAP = 0;
static constexpr size_t MEMSET_BYTES = SZ_BITMAP;              // only the bitmap needs zeroing
static constexpr size_t O_RC     = O_BITMAP + SZ_BITMAP;
static constexpr size_t O_ROFF   = O_RC + SZ_RC;
static constexpr size_t O_DIS    = O_ROFF + SZ_ROFF;
static constexpr size_t O_CSR    = O_DIS + SZ_DIS;
static constexpr size_t O_H1     = O_CSR + SZ_CSR;
static constexpr size_t O_H1A    = O_H1 + SZ_H1;
static constexpr size_t O_G2     = O_H1A + SZ_H1;
static constexpr size_t O_WH     = O_G2 + SZ_G2;
static constexpr size_t O_WL     = O_WH + SZ_WP;
// total ~28.4 MB

// ---------------- helpers ----------------
__device__ inline unsigned short f2bf(float f) {        // f32 -> bf16 bits, RNE
    unsigned u = __float_as_uint(f);
    return (unsigned short)((u + 0x7fffu + ((u >> 16) & 1u)) >> 16);
}
__device__ inline float bf2f(unsigned short h) {
    return __uint_as_float((unsigned)h << 16);
}

// ---------------- graph construction ----------------

// Pure bitmap ingest: one fire-and-forget atomicOr per edge. No counters, no lists.
// int64-vs-int32 layout detect folded in (odd 32-bit words all zero over first 32 values => int64).
__global__ __launch_bounds__(256) void ingest_kernel(const int* __restrict__ e,
        unsigned* __restrict__ bitmap) {
    __shared__ int sflag;
    if (threadIdx.x == 0) {
        int orv = 0;
        #pragma unroll
        for (int j = 1; j < 64; j += 2) orv |= e[j];
        sflag = (orv == 0) ? 1 : 0;
    }
    __syncthreads();
    const int i = blockIdx.x * 256 + threadIdx.x;   // grid exactly covers EE
    int s, d;
    if (sflag) { s = e[2 * i]; d = e[2 * EE + 2 * i]; }   // int64: low words
    else       { s = e[i];     d = e[EE + i]; }            // int32
    const unsigned key = ((unsigned)s << 13) | (unsigned)d;
    atomicOr(&bitmap[key >> 5], 1u << (key & 31u));       // return unused -> no wait
}

// Per-row popcount of the bitmap: block b <-> row b (256 words = one row). No atomics.
__global__ __launch_bounds__(256) void count_kernel(const unsigned* __restrict__ bitmap,
        int* __restrict__ rowc) {
    const int row = blockIdx.x;
    const int t = threadIdx.x;
    int pc = __popc(bitmap[row * 256 + t]);
    #pragma unroll
    for (int o = 32; o > 0; o >>= 1) pc += __shfl_xor(pc, o);   // wave reduce (64 lanes)
    __shared__ int part[4];
    if ((t & 63) == 0) part[t >> 6] = pc;
    __syncthreads();
    if (t == 0) rowc[row] = part[0] + part[1] + part[2] + part[3];
}

// Exclusive prefix sum of row counts (8192) + d_is = rsqrt(deg), deg = count+1 (identity).
__global__ __launch_bounds__(1024) void scan_kernel(const int* __restrict__ rowc,
        int* __restrict__ roff, float* __restrict__ dis) {
    __shared__ int ps[1024];
    const int t = threadIdx.x;
    const int base = t * 8;
    int v[8];
    int s = 0;
    #pragma unroll
    for (int j = 0; j < 8; ++j) { v[j] = rowc[base + j]; s += v[j]; }
    ps[t] = s;
    __syncthreads();
    for (int o = 1; o < 1024; o <<= 1) {
        int add = (t >= o) ? ps[t - o] : 0;
        __syncthreads();
        ps[t] += add;
        __syncthreads();
    }
    int run = ps[t] - s;   // exclusive prefix of this thread's chunk
    #pragma unroll
    for (int j = 0; j < 8; ++j) {
        roff[base + j] = run;
        run += v[j];
        dis[base + j] = rsqrtf((float)(v[j] + 1));
    }
    if (t == 1023) roff[NN] = run;
}

// CSR build from bitmap: block b <-> row b; block-local exclusive prefix over word
// popcounts gives exact slots. No atomics; csr sorted by dst within each row.
__global__ __launch_bounds__(256) void place_kernel(const unsigned* __restrict__ bitmap,
        const int* __restrict__ roff, unsigned* __restrict__ csr) {
    const int row = blockIdx.x;
    const int t = threadIdx.x;
    unsigned wv = bitmap[row * 256 + t];
    const int pc = __popc(wv);
    __shared__ int ps[256];
    ps[t] = pc;
    __syncthreads();
    for (int o = 1; o < 256; o <<= 1) {
        int add = (t >= o) ? ps[t - o] : 0;
        __syncthreads();
        ps[t] += add;
        __syncthreads();
    }
    int pos = roff[row] + ps[t] - pc;   // exclusive prefix
    while (wv) {
        const int b = __ffs(wv) - 1;
        wv &= wv - 1;
        csr[pos++] = (unsigned)(t * 32 + b);
    }
}

// ---------------- W1 split+pack into MFMA B-fragment layout ----------------
// Frag (nfg 0..15, kt 0..31): lane l holds B[k = kt*32 + (l>>4)*8 + j][n = nfg*16 + (l&15)], j=0..7.
__global__ __launch_bounds__(256) void wsplit_kernel(const float* __restrict__ W1,
        unsigned short* __restrict__ Wh, unsigned short* __restrict__ Wl) {
    const int id  = blockIdx.x * 256 + threadIdx.x;   // 0..32767
    const int l   = id & 63;
    const int kt  = (id >> 6) & 31;
    const int nfg = id >> 11;
    const int k0  = kt * 32 + ((l >> 4) << 3);
    const int n   = (nfg << 4) + (l & 15);
    unsigned hh[8], ll[8];
    #pragma unroll
    for (int j = 0; j < 8; ++j) {
        const float f = W1[(size_t)(k0 + j) * HID + n];
        const unsigned short h = f2bf(f);
        hh[j] = h;
        ll[j] = f2bf(f - bf2f(h));
    }
    uint4 vh, vl;
    vh.x = hh[0] | (hh[1] << 16); vh.y = hh[2] | (hh[3] << 16);
    vh.z = hh[4] | (hh[5] << 16); vh.w = hh[6] | (hh[7] << 16);
    vl.x = ll[0] | (ll[1] << 16); vl.y = ll[2] | (ll[3] << 16);
    vl.z = ll[4] | (ll[5] << 16); vl.w = ll[6] | (ll[7] << 16);
    ((uint4*)Wh)[id] = vh;
    ((uint4*)Wl)[id] = vl;
}

// ---------------- GEMM 1: H1 = X @ W1 via split-bf16 MFMA ----------------
// C = Xh*Wh + Xh*Wl + Xl*Wh (f32 accumulate); dropped Xl*Wl term ~2^-18 relative.
// BM=32, BN=128: grid (256,2) -> 2 blocks/CU, 2 waves/SIMD for latency hiding.
// 4 waves/block, wave w owns cols bn*128 + w*32 .. +31 (nf=0..1).
// LDS row stride 264 shorts (132 dwords = 4 mod 32 banks -> 2-way b128 aliasing = free, m136).
static constexpr int RS = 264;

__global__ __launch_bounds__(256) void gemm1_kernel(const float* __restrict__ X,
        const unsigned short* __restrict__ Wh, const unsigned short* __restrict__ Wl,
        float* __restrict__ H) {
    __shared__ unsigned short Ah[32 * RS];
    __shared__ unsigned short Al[32 * RS];
    const int t    = threadIdx.x;
    const int bm   = blockIdx.x;          // 0..255
    const int bn   = blockIdx.y;          // 0..1
    const int lane = t & 63;
    const int w    = t >> 6;              // wave id 0..3
    const int sr = t >> 3;                // staging row 0..31
    const int sc = (t & 7) << 2;          // staging col quad
    const float* Xp = X + (size_t)(bm * 32 + sr) * KIN + sc;
    const short8* Bhp = (const short8*)Wh;
    const short8* Blp = (const short8*)Wl;

    f32x4 acc[2][2];
    #pragma unroll
    for (int mf = 0; mf < 2; ++mf)
        #pragma unroll
        for (int nf = 0; nf < 2; ++nf) acc[mf][nf] = (f32x4)0.f;

    float4 px[8];
    #pragma unroll
    for (int i = 0; i < 8; ++i) px[i] = *(const float4*)(Xp + i * 32);

    // wave's global n-frag base: nfg = bn*8 + w*2 + nf
    const int nfg0 = bn * 8 + w * 2;
    short8 bch[2], bcl[2], bnh[2], bnl[2];
    #pragma unroll
    for (int nf = 0; nf < 2; ++nf) {
        const int fi = ((nfg0 + nf) * 32 + 0) * 64 + lane;
        bch[nf] = Bhp[fi];
        bcl[nf] = Blp[fi];
    }

    for (int ch = 0; ch < 4; ++ch) {
        __syncthreads();
        #pragma unroll
        for (int i = 0; i < 8; ++i) {
            const int k0 = sc + i * 32;
            const float4 v = px[i];
            const float fv[4] = {v.x, v.y, v.z, v.w};
            ushort4 h4, l4;
            unsigned short hs[4], ls[4];
            #pragma unroll
            for (int j = 0; j < 4; ++j) {
                hs[j] = f2bf(fv[j]);
                ls[j] = f2bf(fv[j] - bf2f(hs[j]));
            }
            h4.x = hs[0]; h4.y = hs[1]; h4.z = hs[2]; h4.w = hs[3];
            l4.x = ls[0]; l4.y = ls[1]; l4.z = ls[2]; l4.w = ls[3];
            *(ushort4*)&Ah[sr * RS + k0] = h4;
            *(ushort4*)&Al[sr * RS + k0] = l4;
        }
        __syncthreads();
        if (ch < 3) {
            Xp += 256;
            #pragma unroll
            for (int i = 0; i < 8; ++i) px[i] = *(const float4*)(Xp + i * 32);
        }
        #pragma unroll
        for (int kk = 0; kk < 8; ++kk) {
            const int kt = ch * 8 + kk;
            short8 ah[2], al[2];
            #pragma unroll
            for (int mf = 0; mf < 2; ++mf) {
                const int off = (mf * 16 + (lane & 15)) * RS + kk * 32 + ((lane >> 4) << 3);
                ah[mf] = *(const short8*)&Ah[off];
                al[mf] = *(const short8*)&Al[off];
            }
            if (kt < 31) {
                #pragma unroll
                for (int nf = 0; nf < 2; ++nf) {
                    const int fi = ((nfg0 + nf) * 32 + kt + 1) * 64 + lane;
                    bnh[nf] = Bhp[fi];
                    bnl[nf] = Blp[fi];
                }
            }
            #pragma unroll
            for (int mf = 0; mf < 2; ++mf)
                #pragma unroll
                for (int nf = 0; nf < 2; ++nf) {
                    f32x4 c = acc[mf][nf];
                    c = __builtin_amdgcn_mfma_f32_16x16x32_bf16(ah[mf], bch[nf], c, 0, 0, 0);
                    c = __builtin_amdgcn_mfma_f32_16x16x32_bf16(ah[mf], bcl[nf], c, 0, 0, 0);
                    c = __builtin_amdgcn_mfma_f32_16x16x32_bf16(al[mf], bch[nf], c, 0, 0, 0);
                    acc[mf][nf] = c;
                }
            #pragma unroll
            for (int nf = 0; nf < 2; ++nf) { bch[nf] = bnh[nf]; bcl[nf] = bnl[nf]; }
        }
    }
    // epilogue: C/D layout col=lane&15, row=(lane>>4)*4+r (m89-verified)
    #pragma unroll
    for (int mf = 0; mf < 2; ++mf)
        #pragma unroll
        for (int nf = 0; nf < 2; ++nf)
            #pragma unroll
            for (int r = 0; r < 4; ++r) {
                const int row = bm * 32 + mf * 16 + ((lane >> 4) << 2) + r;
                const int col = bn * 128 + w * 32 + nf * 16 + (lane & 15);
                H[(size_t)row * HID + col] = acc[mf][nf][r];
            }
}

// ---------------- SpMM agg 1 + bias + ReLU ----------------
__global__ __launch_bounds__(256) void agg1_kernel(const float* __restrict__ H1,
        const int* __restrict__ roff, const unsigned* __restrict__ csr,
        const float* __restrict__ dis, const float* __restrict__ b1,
        float* __restrict__ out) {
    __shared__ unsigned dl[256];
    __shared__ float    wl[256];
    const int s = blockIdx.x;
    const int c = threadIdx.x;
    const float ds = dis[s];
    float acc = ds * ds * H1[(size_t)s * HID + c];      // identity term
    const int beg = roff[s], end = roff[s + 1];
    for (int chk = beg; chk < end; chk += 256) {
        const int n = min(256, end - chk);
        __syncthreads();
        if (c < n) {
            const unsigned d = csr[chk + c];
            dl[c] = d;
            wl[c] = ds * dis[d];
        }
        __syncthreads();
        #pragma unroll 4
        for (int i = 0; i < n; ++i)
            acc = fmaf(wl[i], H1[(size_t)dl[i] * HID + c], acc);
    }
    out[(size_t)s * HID + c] = fmaxf(acc + b1[c], 0.f);
}

// ---------------- GEMM 2: G2 = H1A @ W2 (b2 added after agg) ----------------
__global__ __launch_bounds__(256) void gemm2_kernel(const float* __restrict__ H,
        const float* __restrict__ W2, float* __restrict__ G) {
    __shared__ float w2s[HID * NOUT];   // 40 KB
    const int t = threadIdx.x;
    for (int i = t; i < HID * NOUT; i += 256) w2s[i] = W2[i];
    __syncthreads();
    const int row = blockIdx.x * 64 + (t >> 2);
    const int cg  = (t & 3) * 10;
    float acc[10];
    #pragma unroll
    for (int j = 0; j < 10; ++j) acc[j] = 0.f;
    const float* hp = H + (size_t)row * HID;
    for (int k = 0; k < HID; k += 4) {
        const float4 h4 = *(const float4*)(hp + k);
        #pragma unroll
        for (int j = 0; j < 10; ++j) {
            acc[j] = fmaf(h4.x, w2s[(k + 0) * NOUT + cg + j],
                     fmaf(h4.y, w2s[(k + 1) * NOUT + cg + j],
                     fmaf(h4.z, w2s[(k + 2) * NOUT + cg + j],
                     fmaf(h4.w, w2s[(k + 3) * NOUT + cg + j], acc[j]))));
        }
    }
    #pragma unroll
    for (int j = 0; j < 10; ++j) G[(size_t)row * NOUT + cg + j] = acc[j];
}

// ---------------- SpMM agg 2 + b2 + log_softmax, writes d_out ----------------
__global__ __launch_bounds__(256) void agg2_kernel(const float* __restrict__ G,
        const int* __restrict__ roff, const unsigned* __restrict__ csr,
        const float* __restrict__ dis, const float* __restrict__ b2,
        float* __restrict__ out) {
    const int wv   = threadIdx.x >> 6;
    const int lane = threadIdx.x & 63;
    const int s = blockIdx.x * 4 + wv;       // one wave per row
    const bool act = lane < NOUT;
    const float ds = dis[s];
    float acc = act ? ds * ds * G[(size_t)s * NOUT + lane] : 0.f;
    const int beg = roff[s], end = roff[s + 1];
    int e = beg;
    for (; e + 4 <= end; e += 4) {           // unroll x4: batch the dependent loads
        const unsigned d0 = csr[e], d1 = csr[e + 1], d2 = csr[e + 2], d3 = csr[e + 3];
        const float w0 = ds * dis[d0], w1 = ds * dis[d1];
        const float w2 = ds * dis[d2], w3 = ds * dis[d3];
        if (act) {
            const float g0 = G[(size_t)d0 * NOUT + lane];
            const float g1 = G[(size_t)d1 * NOUT + lane];
            const float g2 = G[(size_t)d2 * NOUT + lane];
            const float g3 = G[(size_t)d3 * NOUT + lane];
            acc = fmaf(w0, g0, acc); acc = fmaf(w1, g1, acc);
            acc = fmaf(w2, g2, acc); acc = fmaf(w3, g3, acc);
        }
    }
    for (; e < end; ++e) {
        const unsigned d = csr[e];
        const float wt = ds * dis[d];
        if (act) acc = fmaf(wt, G[(size_t)d * NOUT + lane], acc);
    }
    if (act) acc += b2[lane];
    float v = act ? acc : -INFINITY;
    #pragma unroll
    for (int o = 32; o > 0; o >>= 1) v = fmaxf(v, __shfl_xor(v, o));
    float ex = act ? expf(acc - v) : 0.f;
    #pragma unroll
    for (int o = 32; o > 0; o >>= 1) ex += __shfl_xor(ex, o);
    const float lz = v + logf(ex);
    if (act) out[(size_t)s * NOUT + lane] = acc - lz;
}

// ---------------- launch ----------------
extern "C" void kernel_launch(void* const* d_in, const int* in_sizes, int n_in,
                              void* d_out, int out_size, void* d_ws, size_t ws_size,
                              hipStream_t stream) {
    (void)in_sizes; (void)n_in; (void)out_size; (void)ws_size;
    const float* x  = (const float*)d_in[0];
    const int*   ei = (const int*)d_in[1];
    const float* W1 = (const float*)d_in[2];
    const float* b1 = (const float*)d_in[3];
    const float* W2 = (const float*)d_in[4];
    const float* b2 = (const float*)d_in[5];
    float* out = (float*)d_out;
    char* ws = (char*)d_ws;

    unsigned*       bitmap = (unsigned*)(ws + O_BITMAP);
    int*            rowc   = (int*)(ws + O_RC);
    int*            roff   = (int*)(ws + O_ROFF);
    float*          dis    = (float*)(ws + O_DIS);
    unsigned*       csr    = (unsigned*)(ws + O_CSR);
    float*          H1     = (float*)(ws + O_H1);
    float*          H1A    = (float*)(ws + O_H1A);
    float*          G2     = (float*)(ws + O_G2);
    unsigned short* Wh     = (unsigned short*)(ws + O_WH);
    unsigned short* Wl     = (unsigned short*)(ws + O_WL);

    // zero the dedupe bitmap (ws is re-poisoned to 0xAA before every timed call)
    hipMemsetAsync(ws, 0, MEMSET_BYTES, stream);

    ingest_kernel<<<EE / 256, 256, 0, stream>>>(ei, bitmap);
    count_kernel<<<NN, 256, 0, stream>>>(bitmap, rowc);
    scan_kernel<<<1, 1024, 0, stream>>>(rowc, roff, dis);
    place_kernel<<<NN, 256, 0, stream>>>(bitmap, roff, csr);

    wsplit_kernel<<<(KIN * HID / 8) / 256, 256, 0, stream>>>(W1, Wh, Wl);
    gemm1_kernel<<<dim3(NN / 32, 2), 256, 0, stream>>>(x, Wh, Wl, H1);
    agg1_kernel<<<NN, 256, 0, stream>>>(H1, roff, csr, dis, b1, H1A);
    gemm2_kernel<<<NN / 64, 256, 0, stream>>>(H1A, W2, G2);
    agg2_kernel<<<NN / 4, 256, 0, stream>>>(G2, roff, csr, dis, b2, out);
}

// Round 8
// 176.122 us; speedup vs baseline: 1.4238x; 1.0859x over previous
//
#include <hip/hip_runtime.h>
#include <math.h>

// Problem constants
static constexpr int NN   = 8192;     // nodes
static constexpr int EE   = 262144;   // edges
static constexpr int KIN  = 1024;     // in features
static constexpr int HID  = 256;      // hidden
static constexpr int NOUT = 40;       // out classes

typedef float  f32x4  __attribute__((ext_vector_type(4)));
typedef short  short8 __attribute__((ext_vector_type(8)));

// ---------------- workspace layout (bytes) ----------------
static constexpr size_t SZ_BITMAP = (size_t)NN * NN / 8;       // 8 MB dedupe bitmap
static constexpr size_t SZ_RC     = (size_t)NN * 4;            // row counts
static constexpr size_t SZ_ROFF   = (((size_t)(NN + 1) * 4 + 255) / 256) * 256;
static constexpr size_t SZ_DIS    = (size_t)NN * 4;            // deg^-1/2
static constexpr size_t SZ_CSR    = (size_t)EE * 4;            // csr dst lists
static constexpr size_t SZ_H1B    = (size_t)NN * HID * 2;      // X@W1, bf16 (4 MB)
static constexpr size_t SZ_G2     = (size_t)NN * NOUT * 4;     // H1agg@W2, f32
static constexpr size_t SZ_WP     = (size_t)KIN * HID * 2;     // one bf16 half of W1 pack

static constexpr size_t O_BITMAP = 0;
static constexpr size_t MEMSET_BYTES = SZ_BITMAP;              // only the bitmap needs zeroing
static constexpr size_t O_RC     = O_BITMAP + SZ_BITMAP;
static constexpr size_t O_ROFF   = O_RC + SZ_RC;
static constexpr size_t O_DIS    = O_ROFF + SZ_ROFF;
static constexpr size_t O_CSR    = O_DIS + SZ_DIS;
static constexpr size_t O_H1     = O_CSR + SZ_CSR;             // bf16
static constexpr size_t O_H1A    = O_H1 + SZ_H1B;              // bf16
static constexpr size_t O_G2     = O_H1A + SZ_H1B;
static constexpr size_t O_WH     = O_G2 + SZ_G2;
static constexpr size_t O_WL     = O_WH + SZ_WP;
// total ~20.4 MB

// ---------------- helpers ----------------
__device__ inline unsigned short f2bf(float f) {        // f32 -> bf16 bits, RNE
    unsigned u = __float_as_uint(f);
    return (unsigned short)((u + 0x7fffu + ((u >> 16) & 1u)) >> 16);
}
__device__ inline float bf2f(unsigned short h) {
    return __uint_as_float((unsigned)h << 16);
}

// ---------------- graph construction ----------------

// Pure bitmap ingest: one fire-and-forget atomicOr per edge. No counters, no lists.
// int64-vs-int32 layout detect folded in (odd 32-bit words all zero over first 32 values => int64).
__global__ __launch_bounds__(256) void ingest_kernel(const int* __restrict__ e,
        unsigned* __restrict__ bitmap) {
    __shared__ int sflag;
    if (threadIdx.x == 0) {
        int orv = 0;
        #pragma unroll
        for (int j = 1; j < 64; j += 2) orv |= e[j];
        sflag = (orv == 0) ? 1 : 0;
    }
    __syncthreads();
    const int i = blockIdx.x * 256 + threadIdx.x;   // grid exactly covers EE
    int s, d;
    if (sflag) { s = e[2 * i]; d = e[2 * EE + 2 * i]; }   // int64: low words
    else       { s = e[i];     d = e[EE + i]; }            // int32
    const unsigned key = ((unsigned)s << 13) | (unsigned)d;
    atomicOr(&bitmap[key >> 5], 1u << (key & 31u));       // return unused -> no wait
}

// Per-row popcount of the bitmap: block b <-> row b (256 words = one row). No atomics.
__global__ __launch_bounds__(256) void count_kernel(const unsigned* __restrict__ bitmap,
        int* __restrict__ rowc) {
    const int row = blockIdx.x;
    const int t = threadIdx.x;
    int pc = __popc(bitmap[row * 256 + t]);
    #pragma unroll
    for (int o = 32; o > 0; o >>= 1) pc += __shfl_xor(pc, o);   // wave reduce (64 lanes)
    __shared__ int part[4];
    if ((t & 63) == 0) part[t >> 6] = pc;
    __syncthreads();
    if (t == 0) rowc[row] = part[0] + part[1] + part[2] + part[3];
}

// Exclusive prefix sum of row counts (8192) + d_is = rsqrt(deg), deg = count+1 (identity).
__global__ __launch_bounds__(1024) void scan_kernel(const int* __restrict__ rowc,
        int* __restrict__ roff, float* __restrict__ dis) {
    __shared__ int ps[1024];
    const int t = threadIdx.x;
    const int base = t * 8;
    int v[8];
    int s = 0;
    #pragma unroll
    for (int j = 0; j < 8; ++j) { v[j] = rowc[base + j]; s += v[j]; }
    ps[t] = s;
    __syncthreads();
    for (int o = 1; o < 1024; o <<= 1) {
        int add = (t >= o) ? ps[t - o] : 0;
        __syncthreads();
        ps[t] += add;
        __syncthreads();
    }
    int run = ps[t] - s;   // exclusive prefix of this thread's chunk
    #pragma unroll
    for (int j = 0; j < 8; ++j) {
        roff[base + j] = run;
        run += v[j];
        dis[base + j] = rsqrtf((float)(v[j] + 1));
    }
    if (t == 1023) roff[NN] = run;
}

// CSR build from bitmap: block b <-> row b; block-local exclusive prefix over word
// popcounts gives exact slots. No atomics; csr sorted by dst within each row.
__global__ __launch_bounds__(256) void place_kernel(const unsigned* __restrict__ bitmap,
        const int* __restrict__ roff, unsigned* __restrict__ csr) {
    const int row = blockIdx.x;
    const int t = threadIdx.x;
    unsigned wv = bitmap[row * 256 + t];
    const int pc = __popc(wv);
    __shared__ int ps[256];
    ps[t] = pc;
    __syncthreads();
    for (int o = 1; o < 256; o <<= 1) {
        int add = (t >= o) ? ps[t - o] : 0;
        __syncthreads();
        ps[t] += add;
        __syncthreads();
    }
    int pos = roff[row] + ps[t] - pc;   // exclusive prefix
    while (wv) {
        const int b = __ffs(wv) - 1;
        wv &= wv - 1;
        csr[pos++] = (unsigned)(t * 32 + b);
    }
}

// ---------------- W1 split+pack into MFMA B-fragment layout ----------------
// Frag (nfg 0..15, kt 0..31): lane l holds B[k = kt*32 + (l>>4)*8 + j][n = nfg*16 + (l&15)], j=0..7.
__global__ __launch_bounds__(256) void wsplit_kernel(const float* __restrict__ W1,
        unsigned short* __restrict__ Wh, unsigned short* __restrict__ Wl) {
    const int id  = blockIdx.x * 256 + threadIdx.x;   // 0..32767
    const int l   = id & 63;
    const int kt  = (id >> 6) & 31;
    const int nfg = id >> 11;
    const int k0  = kt * 32 + ((l >> 4) << 3);
    const int n   = (nfg << 4) + (l & 15);
    unsigned hh[8], ll[8];
    #pragma unroll
    for (int j = 0; j < 8; ++j) {
        const float f = W1[(size_t)(k0 + j) * HID + n];
        const unsigned short h = f2bf(f);
        hh[j] = h;
        ll[j] = f2bf(f - bf2f(h));
    }
    uint4 vh, vl;
    vh.x = hh[0] | (hh[1] << 16); vh.y = hh[2] | (hh[3] << 16);
    vh.z = hh[4] | (hh[5] << 16); vh.w = hh[6] | (hh[7] << 16);
    vl.x = ll[0] | (ll[1] << 16); vl.y = ll[2] | (ll[3] << 16);
    vl.z = ll[4] | (ll[5] << 16); vl.w = ll[6] | (ll[7] << 16);
    ((uint4*)Wh)[id] = vh;
    ((uint4*)Wl)[id] = vl;
}

// ---------------- GEMM 1: H1 = X @ W1 via split-bf16 MFMA, bf16 output ----------------
// C = Xh*Wh + Xh*Wl + Xl*Wh (f32 accumulate); dropped Xl*Wl term ~2^-18 relative.
// BM=32, BN=128: grid (256,2) -> 2 blocks/CU, 2 waves/SIMD for latency hiding.
// LDS row stride 264 shorts (132 dwords = 4 mod 32 banks -> 2-way b128 aliasing = free, m136).
static constexpr int RS = 264;

__global__ __launch_bounds__(256) void gemm1_kernel(const float* __restrict__ X,
        const unsigned short* __restrict__ Wh, const unsigned short* __restrict__ Wl,
        unsigned short* __restrict__ H) {
    __shared__ unsigned short Ah[32 * RS];
    __shared__ unsigned short Al[32 * RS];
    const int t    = threadIdx.x;
    const int bm   = blockIdx.x;          // 0..255
    const int bn   = blockIdx.y;          // 0..1
    const int lane = t & 63;
    const int w    = t >> 6;              // wave id 0..3
    const int sr = t >> 3;                // staging row 0..31
    const int sc = (t & 7) << 2;          // staging col quad
    const float* Xp = X + (size_t)(bm * 32 + sr) * KIN + sc;
    const short8* Bhp = (const short8*)Wh;
    const short8* Blp = (const short8*)Wl;

    f32x4 acc[2][2];
    #pragma unroll
    for (int mf = 0; mf < 2; ++mf)
        #pragma unroll
        for (int nf = 0; nf < 2; ++nf) acc[mf][nf] = (f32x4)0.f;

    float4 px[8];
    #pragma unroll
    for (int i = 0; i < 8; ++i) px[i] = *(const float4*)(Xp + i * 32);

    const int nfg0 = bn * 8 + w * 2;      // wave's global n-frag base
    short8 bch[2], bcl[2], bnh[2], bnl[2];
    #pragma unroll
    for (int nf = 0; nf < 2; ++nf) {
        const int fi = ((nfg0 + nf) * 32 + 0) * 64 + lane;
        bch[nf] = Bhp[fi];
        bcl[nf] = Blp[fi];
    }

    for (int ch = 0; ch < 4; ++ch) {
        __syncthreads();
        #pragma unroll
        for (int i = 0; i < 8; ++i) {
            const int k0 = sc + i * 32;
            const float4 v = px[i];
            const float fv[4] = {v.x, v.y, v.z, v.w};
            ushort4 h4, l4;
            unsigned short hs[4], ls[4];
            #pragma unroll
            for (int j = 0; j < 4; ++j) {
                hs[j] = f2bf(fv[j]);
                ls[j] = f2bf(fv[j] - bf2f(hs[j]));
            }
            h4.x = hs[0]; h4.y = hs[1]; h4.z = hs[2]; h4.w = hs[3];
            l4.x = ls[0]; l4.y = ls[1]; l4.z = ls[2]; l4.w = ls[3];
            *(ushort4*)&Ah[sr * RS + k0] = h4;
            *(ushort4*)&Al[sr * RS + k0] = l4;
        }
        __syncthreads();
        if (ch < 3) {
            Xp += 256;
            #pragma unroll
            for (int i = 0; i < 8; ++i) px[i] = *(const float4*)(Xp + i * 32);
        }
        #pragma unroll
        for (int kk = 0; kk < 8; ++kk) {
            const int kt = ch * 8 + kk;
            short8 ah[2], al[2];
            #pragma unroll
            for (int mf = 0; mf < 2; ++mf) {
                const int off = (mf * 16 + (lane & 15)) * RS + kk * 32 + ((lane >> 4) << 3);
                ah[mf] = *(const short8*)&Ah[off];
                al[mf] = *(const short8*)&Al[off];
            }
            if (kt < 31) {
                #pragma unroll
                for (int nf = 0; nf < 2; ++nf) {
                    const int fi = ((nfg0 + nf) * 32 + kt + 1) * 64 + lane;
                    bnh[nf] = Bhp[fi];
                    bnl[nf] = Blp[fi];
                }
            }
            #pragma unroll
            for (int mf = 0; mf < 2; ++mf)
                #pragma unroll
                for (int nf = 0; nf < 2; ++nf) {
                    f32x4 c = acc[mf][nf];
                    c = __builtin_amdgcn_mfma_f32_16x16x32_bf16(ah[mf], bch[nf], c, 0, 0, 0);
                    c = __builtin_amdgcn_mfma_f32_16x16x32_bf16(ah[mf], bcl[nf], c, 0, 0, 0);
                    c = __builtin_amdgcn_mfma_f32_16x16x32_bf16(al[mf], bch[nf], c, 0, 0, 0);
                    acc[mf][nf] = c;
                }
            #pragma unroll
            for (int nf = 0; nf < 2; ++nf) { bch[nf] = bnh[nf]; bcl[nf] = bnl[nf]; }
        }
    }
    // epilogue: C/D layout col=lane&15, row=(lane>>4)*4+r (m89-verified); store bf16
    #pragma unroll
    for (int mf = 0; mf < 2; ++mf)
        #pragma unroll
        for (int nf = 0; nf < 2; ++nf)
            #pragma unroll
            for (int r = 0; r < 4; ++r) {
                const int row = bm * 32 + mf * 16 + ((lane >> 4) << 2) + r;
                const int col = bn * 128 + w * 32 + nf * 16 + (lane & 15);
                H[(size_t)row * HID + col] = f2bf(acc[mf][nf][r]);
            }
}

// ---------------- SpMM agg 1 + bias + ReLU (bf16 in, bf16 out) ----------------
// Wave per row (4 rows/block, no barriers). Lane owns cols 4*lane..+3 (ushort4 = 8B loads).
__global__ __launch_bounds__(256) void agg1_kernel(const unsigned short* __restrict__ H1b,
        const int* __restrict__ roff, const unsigned* __restrict__ csr,
        const float* __restrict__ dis, const float* __restrict__ b1,
        unsigned short* __restrict__ outb) {
    const int w    = threadIdx.x >> 6;
    const int lane = threadIdx.x & 63;
    const int s = blockIdx.x * 4 + w;
    const int c0 = lane * 4;
    const float ds = dis[s];
    const float ds2 = ds * ds;
    ushort4 hv = *(const ushort4*)&H1b[(size_t)s * HID + c0];   // identity term
    float a0 = ds2 * bf2f(hv.x), a1 = ds2 * bf2f(hv.y);
    float a2 = ds2 * bf2f(hv.z), a3 = ds2 * bf2f(hv.w);
    const int beg = roff[s], end = roff[s + 1];
    int e = beg;
    for (; e + 4 <= end; e += 4) {          // unroll x4: batch dependent csr->dis->H1 chains
        const unsigned d0 = csr[e], d1 = csr[e + 1], d2 = csr[e + 2], d3 = csr[e + 3];
        const float w0 = ds * dis[d0], w1 = ds * dis[d1];
        const float w2 = ds * dis[d2], w3 = ds * dis[d3];
        const ushort4 v0 = *(const ushort4*)&H1b[(size_t)d0 * HID + c0];
        const ushort4 v1 = *(const ushort4*)&H1b[(size_t)d1 * HID + c0];
        const ushort4 v2 = *(const ushort4*)&H1b[(size_t)d2 * HID + c0];
        const ushort4 v3 = *(const ushort4*)&H1b[(size_t)d3 * HID + c0];
        a0 = fmaf(w0, bf2f(v0.x), a0); a1 = fmaf(w0, bf2f(v0.y), a1);
        a2 = fmaf(w0, bf2f(v0.z), a2); a3 = fmaf(w0, bf2f(v0.w), a3);
        a0 = fmaf(w1, bf2f(v1.x), a0); a1 = fmaf(w1, bf2f(v1.y), a1);
        a2 = fmaf(w1, bf2f(v1.z), a2); a3 = fmaf(w1, bf2f(v1.w), a3);
        a0 = fmaf(w2, bf2f(v2.x), a0); a1 = fmaf(w2, bf2f(v2.y), a1);
        a2 = fmaf(w2, bf2f(v2.z), a2); a3 = fmaf(w2, bf2f(v2.w), a3);
        a0 = fmaf(w3, bf2f(v3.x), a0); a1 = fmaf(w3, bf2f(v3.y), a1);
        a2 = fmaf(w3, bf2f(v3.z), a2); a3 = fmaf(w3, bf2f(v3.w), a3);
    }
    for (; e < end; ++e) {
        const unsigned d = csr[e];
        const float wt = ds * dis[d];
        const ushort4 v = *(const ushort4*)&H1b[(size_t)d * HID + c0];
        a0 = fmaf(wt, bf2f(v.x), a0); a1 = fmaf(wt, bf2f(v.y), a1);
        a2 = fmaf(wt, bf2f(v.z), a2); a3 = fmaf(wt, bf2f(v.w), a3);
    }
    const float4 bv = *(const float4*)&b1[c0];
    ushort4 o;
    o.x = f2bf(fmaxf(a0 + bv.x, 0.f));
    o.y = f2bf(fmaxf(a1 + bv.y, 0.f));
    o.z = f2bf(fmaxf(a2 + bv.z, 0.f));
    o.w = f2bf(fmaxf(a3 + bv.w, 0.f));
    *(ushort4*)&outb[(size_t)s * HID + c0] = o;
}

// ---------------- GEMM 2: G2 = H1A(bf16) @ W2 (b2 added after agg) ----------------
__global__ __launch_bounds__(256) void gemm2_kernel(const unsigned short* __restrict__ Hb,
        const float* __restrict__ W2, float* __restrict__ G) {
    __shared__ float w2s[HID * NOUT];   // 40 KB
    const int t = threadIdx.x;
    for (int i = t; i < HID * NOUT; i += 256) w2s[i] = W2[i];
    __syncthreads();
    const int row = blockIdx.x * 64 + (t >> 2);
    const int cg  = (t & 3) * 10;
    float acc[10];
    #pragma unroll
    for (int j = 0; j < 10; ++j) acc[j] = 0.f;
    const unsigned short* hp = Hb + (size_t)row * HID;
    for (int k = 0; k < HID; k += 8) {
        const uint4 hv = *(const uint4*)(hp + k);       // 8 bf16
        float h[8];
        h[0] = bf2f((unsigned short)(hv.x & 0xffff)); h[1] = bf2f((unsigned short)(hv.x >> 16));
        h[2] = bf2f((unsigned short)(hv.y & 0xffff)); h[3] = bf2f((unsigned short)(hv.y >> 16));
        h[4] = bf2f((unsigned short)(hv.z & 0xffff)); h[5] = bf2f((unsigned short)(hv.z >> 16));
        h[6] = bf2f((unsigned short)(hv.w & 0xffff)); h[7] = bf2f((unsigned short)(hv.w >> 16));
        #pragma unroll
        for (int i = 0; i < 8; ++i)
            #pragma unroll
            for (int j = 0; j < 10; ++j)
                acc[j] = fmaf(h[i], w2s[(k + i) * NOUT + cg + j], acc[j]);
    }
    #pragma unroll
    for (int j = 0; j < 10; ++j) G[(size_t)row * NOUT + cg + j] = acc[j];
}

// ---------------- SpMM agg 2 + b2 + log_softmax, writes d_out ----------------
__global__ __launch_bounds__(256) void agg2_kernel(const float* __restrict__ G,
        const int* __restrict__ roff, const unsigned* __restrict__ csr,
        const float* __restrict__ dis, const float* __restrict__ b2,
        float* __restrict__ out) {
    const int wv   = threadIdx.x >> 6;
    const int lane = threadIdx.x & 63;
    const int s = blockIdx.x * 4 + wv;       // one wave per row
    const bool act = lane < NOUT;
    const float ds = dis[s];
    float acc = act ? ds * ds * G[(size_t)s * NOUT + lane] : 0.f;
    const int beg = roff[s], end = roff[s + 1];
    int e = beg;
    for (; e + 4 <= end; e += 4) {           // unroll x4: batch the dependent loads
        const unsigned d0 = csr[e], d1 = csr[e + 1], d2 = csr[e + 2], d3 = csr[e + 3];
        const float w0 = ds * dis[d0], w1 = ds * dis[d1];
        const float w2 = ds * dis[d2], w3 = ds * dis[d3];
        if (act) {
            const float g0 = G[(size_t)d0 * NOUT + lane];
            const float g1 = G[(size_t)d1 * NOUT + lane];
            const float g2 = G[(size_t)d2 * NOUT + lane];
            const float g3 = G[(size_t)d3 * NOUT + lane];
            acc = fmaf(w0, g0, acc); acc = fmaf(w1, g1, acc);
            acc = fmaf(w2, g2, acc); acc = fmaf(w3, g3, acc);
        }
    }
    for (; e < end; ++e) {
        const unsigned d = csr[e];
        const float wt = ds * dis[d];
        if (act) acc = fmaf(wt, G[(size_t)d * NOUT + lane], acc);
    }
    if (act) acc += b2[lane];
    float v = act ? acc : -INFINITY;
    #pragma unroll
    for (int o = 32; o > 0; o >>= 1) v = fmaxf(v, __shfl_xor(v, o));
    float ex = act ? expf(acc - v) : 0.f;
    #pragma unroll
    for (int o = 32; o > 0; o >>= 1) ex += __shfl_xor(ex, o);
    const float lz = v + logf(ex);
    if (act) out[(size_t)s * NOUT + lane] = acc - lz;
}

// ---------------- launch ----------------
extern "C" void kernel_launch(void* const* d_in, const int* in_sizes, int n_in,
                              void* d_out, int out_size, void* d_ws, size_t ws_size,
                              hipStream_t stream) {
    (void)in_sizes; (void)n_in; (void)out_size; (void)ws_size;
    const float* x  = (const float*)d_in[0];
    const int*   ei = (const int*)d_in[1];
    const float* W1 = (const float*)d_in[2];
    const float* b1 = (const float*)d_in[3];
    const float* W2 = (const float*)d_in[4];
    const float* b2 = (const float*)d_in[5];
    float* out = (float*)d_out;
    char* ws = (char*)d_ws;

    unsigned*       bitmap = (unsigned*)(ws + O_BITMAP);
    int*            rowc   = (int*)(ws + O_RC);
    int*            roff   = (int*)(ws + O_ROFF);
    float*          dis    = (float*)(ws + O_DIS);
    unsigned*       csr    = (unsigned*)(ws + O_CSR);
    unsigned short* H1     = (unsigned short*)(ws + O_H1);
    unsigned short* H1A    = (unsigned short*)(ws + O_H1A);
    float*          G2     = (float*)(ws + O_G2);
    unsigned short* Wh     = (unsigned short*)(ws + O_WH);
    unsigned short* Wl     = (unsigned short*)(ws + O_WL);

    // zero the dedupe bitmap (ws is re-poisoned to 0xAA before every timed call)
    hipMemsetAsync(ws, 0, MEMSET_BYTES, stream);

    ingest_kernel<<<EE / 256, 256, 0, stream>>>(ei, bitmap);
    count_kernel<<<NN, 256, 0, stream>>>(bitmap, rowc);
    scan_kernel<<<1, 1024, 0, stream>>>(rowc, roff, dis);
    place_kernel<<<NN, 256, 0, stream>>>(bitmap, roff, csr);

    wsplit_kernel<<<(KIN * HID / 8) / 256, 256, 0, stream>>>(W1, Wh, Wl);
    gemm1_kernel<<<dim3(NN / 32, 2), 256, 0, stream>>>(x, Wh, Wl, H1);
    agg1_kernel<<<NN / 4, 256, 0, stream>>>(H1, roff, csr, dis, b1, H1A);
    gemm2_kernel<<<NN / 64, 256, 0, stream>>>(H1A, W2, G2);
    agg2_kernel<<<NN / 4, 256, 0, stream>>>(G2, roff, csr, dis, b2, out);
}

// Round 11
// 172.091 us; speedup vs baseline: 1.4571x; 1.0234x over previous
//
#include <hip/hip_runtime.h>
#include <math.h>

// Problem constants
static constexpr int NN   = 8192;     // nodes
static constexpr int EE   = 262144;   // edges
static constexpr int KIN  = 1024;     // in features
static constexpr int HID  = 256;      // hidden
static constexpr int NOUT = 40;       // out classes

typedef float  f32x4  __attribute__((ext_vector_type(4)));
typedef short  short8 __attribute__((ext_vector_type(8)));

// ---------------- workspace layout (bytes) ----------------
static constexpr size_t SZ_BITMAP = (size_t)NN * NN / 8;       // 8 MB dedupe bitmap
static constexpr size_t SZ_RC     = (size_t)NN * 4;            // row counts
static constexpr size_t SZ_ROFF   = (((size_t)(NN + 1) * 4 + 255) / 256) * 256;
static constexpr size_t SZ_DIS    = (size_t)NN * 4;            // deg^-1/2
static constexpr size_t SZ_CSR    = (size_t)EE * 4;            // csr dst lists
static constexpr size_t SZ_H1B    = (size_t)NN * HID * 2;      // X@W1, bf16 (4 MB)
static constexpr size_t SZ_G2     = (size_t)NN * NOUT * 4;     // H1agg@W2, f32
static constexpr size_t SZ_WP     = (size_t)KIN * HID * 2;     // one bf16 half of W1 pack

static constexpr size_t O_BITMAP = 0;
static constexpr size_t MEMSET_BYTES = SZ_BITMAP;              // only the bitmap needs zeroing
static constexpr size_t O_RC     = O_BITMAP + SZ_BITMAP;
static constexpr size_t O_ROFF   = O_RC + SZ_RC;
static constexpr size_t O_DIS    = O_ROFF + SZ_ROFF;
static constexpr size_t O_CSR    = O_DIS + SZ_DIS;
static constexpr size_t O_H1     = O_CSR + SZ_CSR;             // bf16
static constexpr size_t O_H1A    = O_H1 + SZ_H1B;              // bf16
static constexpr size_t O_G2     = O_H1A + SZ_H1B;
static constexpr size_t O_WH     = O_G2 + SZ_G2;
static constexpr size_t O_WL     = O_WH + SZ_WP;
// total ~20.4 MB

// ---------------- helpers ----------------
__device__ inline unsigned short f2bf(float f) {        // f32 -> bf16 bits, RNE
    unsigned u = __float_as_uint(f);
    return (unsigned short)((u + 0x7fffu + ((u >> 16) & 1u)) >> 16);
}
__device__ inline float bf2f(unsigned short h) {
    return __uint_as_float((unsigned)h << 16);
}

// ---------------- graph construction ----------------

// Pure bitmap ingest: one fire-and-forget atomicOr per edge. No counters, no lists.
// int64-vs-int32 layout detect folded in (odd 32-bit words all zero over first 32 values => int64).
__global__ __launch_bounds__(256) void ingest_kernel(const int* __restrict__ e,
        unsigned* __restrict__ bitmap) {
    __shared__ int sflag;
    if (threadIdx.x == 0) {
        int orv = 0;
        #pragma unroll
        for (int j = 1; j < 64; j += 2) orv |= e[j];
        sflag = (orv == 0) ? 1 : 0;
    }
    __syncthreads();
    const int i = blockIdx.x * 256 + threadIdx.x;   // grid exactly covers EE
    int s, d;
    if (sflag) { s = e[2 * i]; d = e[2 * EE + 2 * i]; }   // int64: low words
    else       { s = e[i];     d = e[EE + i]; }            // int32
    const unsigned key = ((unsigned)s << 13) | (unsigned)d;
    atomicOr(&bitmap[key >> 5], 1u << (key & 31u));       // return unused -> no wait
}

// Per-row popcount of the bitmap: block b <-> row b (256 words = one row). No atomics.
__global__ __launch_bounds__(256) void count_kernel(const unsigned* __restrict__ bitmap,
        int* __restrict__ rowc) {
    const int row = blockIdx.x;
    const int t = threadIdx.x;
    int pc = __popc(bitmap[row * 256 + t]);
    #pragma unroll
    for (int o = 32; o > 0; o >>= 1) pc += __shfl_xor(pc, o);   // wave reduce (64 lanes)
    __shared__ int part[4];
    if ((t & 63) == 0) part[t >> 6] = pc;
    __syncthreads();
    if (t == 0) rowc[row] = part[0] + part[1] + part[2] + part[3];
}

// Exclusive prefix sum of row counts (8192) + d_is = rsqrt(deg), deg = count+1 (identity).
__global__ __launch_bounds__(1024) void scan_kernel(const int* __restrict__ rowc,
        int* __restrict__ roff, float* __restrict__ dis) {
    __shared__ int ps[1024];
    const int t = threadIdx.x;
    const int base = t * 8;
    int v[8];
    int s = 0;
    #pragma unroll
    for (int j = 0; j < 8; ++j) { v[j] = rowc[base + j]; s += v[j]; }
    ps[t] = s;
    __syncthreads();
    for (int o = 1; o < 1024; o <<= 1) {
        int add = (t >= o) ? ps[t - o] : 0;
        __syncthreads();
        ps[t] += add;
        __syncthreads();
    }
    int run = ps[t] - s;   // exclusive prefix of this thread's chunk
    #pragma unroll
    for (int j = 0; j < 8; ++j) {
        roff[base + j] = run;
        run += v[j];
        dis[base + j] = rsqrtf((float)(v[j] + 1));
    }
    if (t == 1023) roff[NN] = run;
}

// CSR build from bitmap: block b <-> row b; block-local exclusive prefix over word
// popcounts gives exact slots. No atomics; csr sorted by dst within each row.
__global__ __launch_bounds__(256) void place_kernel(const unsigned* __restrict__ bitmap,
        const int* __restrict__ roff, unsigned* __restrict__ csr) {
    const int row = blockIdx.x;
    const int t = threadIdx.x;
    unsigned wv = bitmap[row * 256 + t];
    const int pc = __popc(wv);
    __shared__ int ps[256];
    ps[t] = pc;
    __syncthreads();
    for (int o = 1; o < 256; o <<= 1) {
        int add = (t >= o) ? ps[t - o] : 0;
        __syncthreads();
        ps[t] += add;
        __syncthreads();
    }
    int pos = roff[row] + ps[t] - pc;   // exclusive prefix
    while (wv) {
        const int b = __ffs(wv) - 1;
        wv &= wv - 1;
        csr[pos++] = (unsigned)(t * 32 + b);
    }
}

// ---------------- W1 split+pack into MFMA B-fragment layout ----------------
// Frag (nfg 0..15, kt 0..31): lane l holds B[k = kt*32 + (l>>4)*8 + j][n = nfg*16 + (l&15)], j=0..7.
__global__ __launch_bounds__(256) void wsplit_kernel(const float* __restrict__ W1,
        unsigned short* __restrict__ Wh, unsigned short* __restrict__ Wl) {
    const int id  = blockIdx.x * 256 + threadIdx.x;   // 0..32767
    const int l   = id & 63;
    const int kt  = (id >> 6) & 31;
    const int nfg = id >> 11;
    const int k0  = kt * 32 + ((l >> 4) << 3);
    const int n   = (nfg << 4) + (l & 15);
    unsigned hh[8], ll[8];
    #pragma unroll
    for (int j = 0; j < 8; ++j) {
        const float f = W1[(size_t)(k0 + j) * HID + n];
        const unsigned short h = f2bf(f);
        hh[j] = h;
        ll[j] = f2bf(f - bf2f(h));
    }
    uint4 vh, vl;
    vh.x = hh[0] | (hh[1] << 16); vh.y = hh[2] | (hh[3] << 16);
    vh.z = hh[4] | (hh[5] << 16); vh.w = hh[6] | (hh[7] << 16);
    vl.x = ll[0] | (ll[1] << 16); vl.y = ll[2] | (ll[3] << 16);
    vl.z = ll[4] | (ll[5] << 16); vl.w = ll[6] | (ll[7] << 16);
    ((uint4*)Wh)[id] = vh;
    ((uint4*)Wl)[id] = vl;
}

// ---------------- GEMM 1: H1 = X @ W1 via split-bf16 MFMA, bf16 output ----------------
// C = Xh*Wh + Xh*Wl + Xl*Wh (f32 accumulate); dropped Xl*Wl term ~2^-18 relative.
// BM=32, BN=128, 512 threads (8 waves): grid (256,2) = 512 blocks -> 2 blocks/CU,
// 16 waves/CU = 4 waves/SIMD for latency hiding. Wave w owns n-frag nfg = bn*8+w.
// Same fragments / MFMA order as R8 -> H1 bitwise identical (schedule-only change).
// LDS row stride 264 shorts (132 dwords = 4 mod 32 banks -> 2-way b128 aliasing = free, m136).
static constexpr int RS = 264;

__global__ __launch_bounds__(512, 4) void gemm1_kernel(const float* __restrict__ X,
        const unsigned short* __restrict__ Wh, const unsigned short* __restrict__ Wl,
        unsigned short* __restrict__ H) {
    __shared__ unsigned short Ah[32 * RS];
    __shared__ unsigned short Al[32 * RS];
    const int t    = threadIdx.x;
    const int bm   = blockIdx.x;          // 0..255
    const int bn   = blockIdx.y;          // 0..1
    const int lane = t & 63;
    const int w    = t >> 6;              // wave id 0..7
    const int sr = t >> 4;                // staging row 0..31 (16 threads/row)
    const int sc = (t & 15) << 2;         // staging col quad 0..60
    const float* Xp = X + (size_t)(bm * 32 + sr) * KIN + sc;
    const short8* Bhp = (const short8*)Wh;
    const short8* Blp = (const short8*)Wl;

    f32x4 acc[2];
    acc[0] = (f32x4)0.f;
    acc[1] = (f32x4)0.f;

    float4 px[4];
    #pragma unroll
    for (int i = 0; i < 4; ++i) px[i] = *(const float4*)(Xp + i * 64);

    const int nfg = bn * 8 + w;           // wave's n-frag
    short8 bch, bcl, bnh, bnl;
    {
        const int fi = (nfg * 32 + 0) * 64 + lane;
        bch = Bhp[fi];
        bcl = Blp[fi];
    }

    for (int ch = 0; ch < 4; ++ch) {
        __syncthreads();
        #pragma unroll
        for (int i = 0; i < 4; ++i) {
            const int k0 = sc + i * 64;
            const float4 v = px[i];
            const float fv[4] = {v.x, v.y, v.z, v.w};
            ushort4 h4, l4;
            unsigned short hs[4], ls[4];
            #pragma unroll
            for (int j = 0; j < 4; ++j) {
                hs[j] = f2bf(fv[j]);
                ls[j] = f2bf(fv[j] - bf2f(hs[j]));
            }
            h4.x = hs[0]; h4.y = hs[1]; h4.z = hs[2]; h4.w = hs[3];
            l4.x = ls[0]; l4.y = ls[1]; l4.z = ls[2]; l4.w = ls[3];
            *(ushort4*)&Ah[sr * RS + k0] = h4;
            *(ushort4*)&Al[sr * RS + k0] = l4;
        }
        __syncthreads();
        if (ch < 3) {
            Xp += 256;
            #pragma unroll
            for (int i = 0; i < 4; ++i) px[i] = *(const float4*)(Xp + i * 64);
        }
        #pragma unroll
        for (int kk = 0; kk < 8; ++kk) {
            const int kt = ch * 8 + kk;
            short8 ah[2], al[2];
            #pragma unroll
            for (int mf = 0; mf < 2; ++mf) {
                const int off = (mf * 16 + (lane & 15)) * RS + kk * 32 + ((lane >> 4) << 3);
                ah[mf] = *(const short8*)&Ah[off];
                al[mf] = *(const short8*)&Al[off];
            }
            if (kt < 31) {
                const int fi = (nfg * 32 + kt + 1) * 64 + lane;
                bnh = Bhp[fi];
                bnl = Blp[fi];
            }
            #pragma unroll
            for (int mf = 0; mf < 2; ++mf) {
                f32x4 c = acc[mf];
                c = __builtin_amdgcn_mfma_f32_16x16x32_bf16(ah[mf], bch, c, 0, 0, 0);
                c = __builtin_amdgcn_mfma_f32_16x16x32_bf16(ah[mf], bcl, c, 0, 0, 0);
                c = __builtin_amdgcn_mfma_f32_16x16x32_bf16(al[mf], bch, c, 0, 0, 0);
                acc[mf] = c;
            }
            bch = bnh;
            bcl = bnl;
        }
    }
    // epilogue: C/D layout col=lane&15, row=(lane>>4)*4+r (m89-verified); store bf16
    #pragma unroll
    for (int mf = 0; mf < 2; ++mf)
        #pragma unroll
        for (int r = 0; r < 4; ++r) {
            const int row = bm * 32 + mf * 16 + ((lane >> 4) << 2) + r;
            const int col = bn * 128 + w * 16 + (lane & 15);
            H[(size_t)row * HID + col] = f2bf(acc[mf][r]);
        }
}

// ---------------- SpMM agg 1 + bias + ReLU (bf16 in, bf16 out) ----------------
// Wave per row (4 rows/block, no barriers). Lane owns cols 4*lane..+3 (ushort4 = 8B loads).
__global__ __launch_bounds__(256) void agg1_kernel(const unsigned short* __restrict__ H1b,
        const int* __restrict__ roff, const unsigned* __restrict__ csr,
        const float* __restrict__ dis, const float* __restrict__ b1,
        unsigned short* __restrict__ outb) {
    const int w    = threadIdx.x >> 6;
    const int lane = threadIdx.x & 63;
    const int s = blockIdx.x * 4 + w;
    const int c0 = lane * 4;
    const float ds = dis[s];
    const float ds2 = ds * ds;
    ushort4 hv = *(const ushort4*)&H1b[(size_t)s * HID + c0];   // identity term
    float a0 = ds2 * bf2f(hv.x), a1 = ds2 * bf2f(hv.y);
    float a2 = ds2 * bf2f(hv.z), a3 = ds2 * bf2f(hv.w);
    const int beg = roff[s], end = roff[s + 1];
    int e = beg;
    for (; e + 4 <= end; e += 4) {          // unroll x4: batch dependent csr->dis->H1 chains
        const unsigned d0 = csr[e], d1 = csr[e + 1], d2 = csr[e + 2], d3 = csr[e + 3];
        const float w0 = ds * dis[d0], w1 = ds * dis[d1];
        const float w2 = ds * dis[d2], w3 = ds * dis[d3];
        const ushort4 v0 = *(const ushort4*)&H1b[(size_t)d0 * HID + c0];
        const ushort4 v1 = *(const ushort4*)&H1b[(size_t)d1 * HID + c0];
        const ushort4 v2 = *(const ushort4*)&H1b[(size_t)d2 * HID + c0];
        const ushort4 v3 = *(const ushort4*)&H1b[(size_t)d3 * HID + c0];
        a0 = fmaf(w0, bf2f(v0.x), a0); a1 = fmaf(w0, bf2f(v0.y), a1);
        a2 = fmaf(w0, bf2f(v0.z), a2); a3 = fmaf(w0, bf2f(v0.w), a3);
        a0 = fmaf(w1, bf2f(v1.x), a0); a1 = fmaf(w1, bf2f(v1.y), a1);
        a2 = fmaf(w1, bf2f(v1.z), a2); a3 = fmaf(w1, bf2f(v1.w), a3);
        a0 = fmaf(w2, bf2f(v2.x), a0); a1 = fmaf(w2, bf2f(v2.y), a1);
        a2 = fmaf(w2, bf2f(v2.z), a2); a3 = fmaf(w2, bf2f(v2.w), a3);
        a0 = fmaf(w3, bf2f(v3.x), a0); a1 = fmaf(w3, bf2f(v3.y), a1);
        a2 = fmaf(w3, bf2f(v3.z), a2); a3 = fmaf(w3, bf2f(v3.w), a3);
    }
    for (; e < end; ++e) {
        const unsigned d = csr[e];
        const float wt = ds * dis[d];
        const ushort4 v = *(const ushort4*)&H1b[(size_t)d * HID + c0];
        a0 = fmaf(wt, bf2f(v.x), a0); a1 = fmaf(wt, bf2f(v.y), a1);
        a2 = fmaf(wt, bf2f(v.z), a2); a3 = fmaf(wt, bf2f(v.w), a3);
    }
    const float4 bv = *(const float4*)&b1[c0];
    ushort4 o;
    o.x = f2bf(fmaxf(a0 + bv.x, 0.f));
    o.y = f2bf(fmaxf(a1 + bv.y, 0.f));
    o.z = f2bf(fmaxf(a2 + bv.z, 0.f));
    o.w = f2bf(fmaxf(a3 + bv.w, 0.f));
    *(ushort4*)&outb[(size_t)s * HID + c0] = o;
}

// ---------------- GEMM 2: G2 = H1A(bf16) @ W2 (b2 added after agg) ----------------
__global__ __launch_bounds__(256) void gemm2_kernel(const unsigned short* __restrict__ Hb,
        const float* __restrict__ W2, float* __restrict__ G) {
    __shared__ float w2s[HID * NOUT];   // 40 KB
    const int t = threadIdx.x;
    for (int i = t; i < HID * NOUT; i += 256) w2s[i] = W2[i];
    __syncthreads();
    const int row = blockIdx.x * 64 + (t >> 2);
    const int cg  = (t & 3) * 10;
    float acc[10];
    #pragma unroll
    for (int j = 0; j < 10; ++j) acc[j] = 0.f;
    const unsigned short* hp = Hb + (size_t)row * HID;
    for (int k = 0; k < HID; k += 8) {
        const uint4 hv = *(const uint4*)(hp + k);       // 8 bf16
        float h[8];
        h[0] = bf2f((unsigned short)(hv.x & 0xffff)); h[1] = bf2f((unsigned short)(hv.x >> 16));
        h[2] = bf2f((unsigned short)(hv.y & 0xffff)); h[3] = bf2f((unsigned short)(hv.y >> 16));
        h[4] = bf2f((unsigned short)(hv.z & 0xffff)); h[5] = bf2f((unsigned short)(hv.z >> 16));
        h[6] = bf2f((unsigned short)(hv.w & 0xffff)); h[7] = bf2f((unsigned short)(hv.w >> 16));
        #pragma unroll
        for (int i = 0; i < 8; ++i)
            #pragma unroll
            for (int j = 0; j < 10; ++j)
                acc[j] = fmaf(h[i], w2s[(k + i) * NOUT + cg + j], acc[j]);
    }
    #pragma unroll
    for (int j = 0; j < 10; ++j) G[(size_t)row * NOUT + cg + j] = acc[j];
}

// ---------------- SpMM agg 2 + b2 + log_softmax, writes d_out ----------------
__global__ __launch_bounds__(256) void agg2_kernel(const float* __restrict__ G,
        const int* __restrict__ roff, const unsigned* __restrict__ csr,
        const float* __restrict__ dis, const float* __restrict__ b2,
        float* __restrict__ out) {
    const int wv   = threadIdx.x >> 6;
    const int lane = threadIdx.x & 63;
    const int s = blockIdx.x * 4 + wv;       // one wave per row
    const bool act = lane < NOUT;
    const float ds = dis[s];
    float acc = act ? ds * ds * G[(size_t)s * NOUT + lane] : 0.f;
    const int beg = roff[s], end = roff[s + 1];
    int e = beg;
    for (; e + 4 <= end; e += 4) {           // unroll x4: batch the dependent loads
        const unsigned d0 = csr[e], d1 = csr[e + 1], d2 = csr[e + 2], d3 = csr[e + 3];
        const float w0 = ds * dis[d0], w1 = ds * dis[d1];
        const float w2 = ds * dis[d2], w3 = ds * dis[d3];
        if (act) {
            const float g0 = G[(size_t)d0 * NOUT + lane];
            const float g1 = G[(size_t)d1 * NOUT + lane];
            const float g2 = G[(size_t)d2 * NOUT + lane];
            const float g3 = G[(size_t)d3 * NOUT + lane];
            acc = fmaf(w0, g0, acc); acc = fmaf(w1, g1, acc);
            acc = fmaf(w2, g2, acc); acc = fmaf(w3, g3, acc);
        }
    }
    for (; e < end; ++e) {
        const unsigned d = csr[e];
        const float wt = ds * dis[d];
        if (act) acc = fmaf(wt, G[(size_t)d * NOUT + lane], acc);
    }
    if (act) acc += b2[lane];
    float v = act ? acc : -INFINITY;
    #pragma unroll
    for (int o = 32; o > 0; o >>= 1) v = fmaxf(v, __shfl_xor(v, o));
    float ex = act ? expf(acc - v) : 0.f;
    #pragma unroll
    for (int o = 32; o > 0; o >>= 1) ex += __shfl_xor(ex, o);
    const float lz = v + logf(ex);
    if (act) out[(size_t)s * NOUT + lane] = acc - lz;
}

// ---------------- launch ----------------
extern "C" void kernel_launch(void* const* d_in, const int* in_sizes, int n_in,
                              void* d_out, int out_size, void* d_ws, size_t ws_size,
                              hipStream_t stream) {
    (void)in_sizes; (void)n_in; (void)out_size; (void)ws_size;
    const float* x  = (const float*)d_in[0];
    const int*   ei = (const int*)d_in[1];
    const float* W1 = (const float*)d_in[2];
    const float* b1 = (const float*)d_in[3];
    const float* W2 = (const float*)d_in[4];
    const float* b2 = (const float*)d_in[5];
    float* out = (float*)d_out;
    char* ws = (char*)d_ws;

    unsigned*       bitmap = (unsigned*)(ws + O_BITMAP);
    int*            rowc   = (int*)(ws + O_RC);
    int*            roff   = (int*)(ws + O_ROFF);
    float*          dis    = (float*)(ws + O_DIS);
    unsigned*       csr    = (unsigned*)(ws + O_CSR);
    unsigned short* H1     = (unsigned short*)(ws + O_H1);
    unsigned short* H1A    = (unsigned short*)(ws + O_H1A);
    float*          G2     = (float*)(ws + O_G2);
    unsigned short* Wh     = (unsigned short*)(ws + O_WH);
    unsigned short* Wl     = (unsigned short*)(ws + O_WL);

    // zero the dedupe bitmap (ws is re-poisoned to 0xAA before every timed call)
    hipMemsetAsync(ws, 0, MEMSET_BYTES, stream);

    ingest_kernel<<<EE / 256, 256, 0, stream>>>(ei, bitmap);
    count_kernel<<<NN, 256, 0, stream>>>(bitmap, rowc);
    scan_kernel<<<1, 1024, 0, stream>>>(rowc, roff, dis);
    place_kernel<<<NN, 256, 0, stream>>>(bitmap, roff, csr);

    wsplit_kernel<<<(KIN * HID / 8) / 256, 256, 0, stream>>>(W1, Wh, Wl);
    gemm1_kernel<<<dim3(NN / 32, 2), 512, 0, stream>>>(x, Wh, Wl, H1);
    agg1_kernel<<<NN / 4, 256, 0, stream>>>(H1, roff, csr, dis, b1, H1A);
    gemm2_kernel<<<NN / 64, 256, 0, stream>>>(H1A, W2, G2);
    agg2_kernel<<<NN / 4, 256, 0, stream>>>(G2, roff, csr, dis, b2, out);
}